// Round 1
// baseline (4496.898 us; speedup 1.0000x reference)
//
#include <hip/hip_runtime.h>

// FusedMoE: T=8192 tokens, E=8 experts, H=2048, I=5632, top_k=2.
// fp32 in/out, bf16 MFMA compute internally (2% relative absmax budget).

#define T_TOK 8192
#define NE 8
#define NH 2048
#define NI 5632
#define NS (T_TOK * 2)   // total (token, expert-slot) rows

typedef float f32x4 __attribute__((ext_vector_type(4)));
typedef __bf16 bf16x8 __attribute__((ext_vector_type(8)));
typedef unsigned short ushort8v __attribute__((ext_vector_type(8)));

__device__ __forceinline__ unsigned short f2bf(float f) {
    unsigned int u = __builtin_bit_cast(unsigned int, f);
    u += 0x7fffu + ((u >> 16) & 1u);   // round-to-nearest-even
    return (unsigned short)(u >> 16);
}
__device__ __forceinline__ float bf2f(unsigned short h) {
    unsigned int u = ((unsigned int)h) << 16;
    return __builtin_bit_cast(float, u);
}

// ---------------- prep: x fp32 -> bf16, zero routing counters ----------------
__global__ __launch_bounds__(256) void k_prep(const float* __restrict__ x,
                                              unsigned short* __restrict__ xbf,
                                              int* __restrict__ counts,
                                              int* __restrict__ pos) {
    int gid = blockIdx.x * 256 + threadIdx.x;
    if (gid < 2 * NE) {
        if (gid < NE) counts[gid] = 0;
        else pos[gid - NE] = 0;
    }
    const float4 v = *(const float4*)(x + (size_t)gid * 4);
    ushort4 o;
    o.x = f2bf(v.x); o.y = f2bf(v.y); o.z = f2bf(v.z); o.w = f2bf(v.w);
    *(ushort4*)(xbf + (size_t)gid * 4) = o;
}

// ---------------- router: top-2 + softmax over selected logits ----------------
__global__ __launch_bounds__(256) void k_router(const float* __restrict__ rl,
                                                int* __restrict__ tid2,
                                                float* __restrict__ tw2,
                                                int* __restrict__ counts) {
    int t = blockIdx.x * 256 + threadIdx.x;
    if (t >= T_TOK) return;
    float v[NE];
    const float4 a = *(const float4*)(rl + (size_t)t * NE);
    const float4 b = *(const float4*)(rl + (size_t)t * NE + 4);
    v[0] = a.x; v[1] = a.y; v[2] = a.z; v[3] = a.w;
    v[4] = b.x; v[5] = b.y; v[6] = b.z; v[7] = b.w;
    int b0 = 0; float m0 = v[0];
#pragma unroll
    for (int j = 1; j < NE; ++j)
        if (v[j] > m0) { m0 = v[j]; b0 = j; }   // first max wins ties (jax top_k)
    int b1 = -1; float m1 = -3.4e38f;
#pragma unroll
    for (int j = 0; j < NE; ++j)
        if (j != b0 && v[j] > m1) { m1 = v[j]; b1 = j; }
    float e1 = __expf(m1 - m0);
    float inv = 1.0f / (1.0f + e1);
    tid2[2 * t] = b0; tid2[2 * t + 1] = b1;
    tw2[2 * t] = inv; tw2[2 * t + 1] = e1 * inv;
    atomicAdd(&counts[b0], 1);
    atomicAdd(&counts[b1], 1);
}

// ---------------- scan: exclusive prefix sum over E=8 counts ----------------
__global__ void k_scan(const int* __restrict__ counts, int* __restrict__ offs) {
    if (threadIdx.x == 0) {
        int s = 0;
        for (int e = 0; e < NE; ++e) { offs[e] = s; s += counts[e]; }
    }
}

// ---------------- scatter: build per-expert token lists ----------------
__global__ __launch_bounds__(256) void k_scatter(const int* __restrict__ tid2,
                                                 const int* __restrict__ offs,
                                                 int* __restrict__ pos,
                                                 int* __restrict__ sorted_tok,
                                                 int* __restrict__ slot_pos) {
    int g = blockIdx.x * 256 + threadIdx.x;
    if (g >= NS) return;
    int t = g >> 1;
    int e = tid2[g];
    int p = offs[e] + atomicAdd(&pos[e], 1);
    sorted_tok[p] = t;
    slot_pos[g] = p;
}

// ---------------- pass 1: act = silu(x@w1^T) * (x@w3^T), gathered per expert --
// Block tile: 128 rows (tokens) x 64 cols (I), BK=64. 4 waves in 2x2,
// wave tile 64x32, each wave 4x2 mfma_f32_16x16x32_bf16 frags per matrix.
__global__ __launch_bounds__(256) void k_up(
    const unsigned short* __restrict__ xbf,
    const float* __restrict__ w1, const float* __restrict__ w3,
    const int* __restrict__ sorted_tok, const int* __restrict__ offs,
    const int* __restrict__ counts, unsigned short* __restrict__ act) {
    const int e = blockIdx.z;
    const int cnt = counts[e];
    const int row0 = blockIdx.x * 128;
    if (row0 >= cnt) return;
    const int i0 = blockIdx.y * 64;
    const int off = offs[e];

    __shared__ unsigned short sA[128][72];   // +8 pad: 2-way LDS conflicts only
    __shared__ unsigned short sB1[64][72];
    __shared__ unsigned short sB2[64][72];

    const int tid = threadIdx.x;
    const int lane = tid & 63, wid = tid >> 6;
    const int wm = wid & 1, wn = wid >> 1;
    const int quad = lane >> 4, l16 = lane & 15;

    const f32x4 zf = {0.f, 0.f, 0.f, 0.f};
    f32x4 accg[4][2], accu[4][2];
#pragma unroll
    for (int mi = 0; mi < 4; ++mi)
#pragma unroll
        for (int ni = 0; ni < 2; ++ni) { accg[mi][ni] = zf; accu[mi][ni] = zf; }

    // A staging: 32 rows/iter x 8 threads/row (8 bf16 = 16B each), 4 iters
    const int ar = tid >> 3;
    const int ak = (tid & 7) * 8;
    const unsigned short* pa[4];
#pragma unroll
    for (int it = 0; it < 4; ++it) {
        int rr = row0 + ar + it * 32;
        int p = off + (rr < cnt ? rr : cnt - 1);   // clamp; masked at store
        pa[it] = xbf + (size_t)sorted_tok[p] * NH + ak;
    }
    // B staging: 16 rows/iter x 16 threads/row (4 fp32 = 16B each), 4 iters
    const int br = tid >> 4;
    const int bk = (tid & 15) * 4;
    const float* pw1 = w1 + ((size_t)e * NI + i0 + br) * NH + bk;
    const float* pw3 = w3 + ((size_t)e * NI + i0 + br) * NH + bk;

    for (int k0 = 0; k0 < NH; k0 += 64) {
#pragma unroll
        for (int it = 0; it < 4; ++it) {
            const uint4 v = *(const uint4*)(pa[it] + k0);
            *(uint4*)(&sA[ar + it * 32][ak]) = v;
        }
#pragma unroll
        for (int it = 0; it < 4; ++it) {
            const float4 v1 = *(const float4*)(pw1 + (size_t)(it * 16) * NH + k0);
            const float4 v3 = *(const float4*)(pw3 + (size_t)(it * 16) * NH + k0);
            ushort4 c1, c3;
            c1.x = f2bf(v1.x); c1.y = f2bf(v1.y); c1.z = f2bf(v1.z); c1.w = f2bf(v1.w);
            c3.x = f2bf(v3.x); c3.y = f2bf(v3.y); c3.z = f2bf(v3.z); c3.w = f2bf(v3.w);
            *(ushort4*)(&sB1[br + it * 16][bk]) = c1;
            *(ushort4*)(&sB2[br + it * 16][bk]) = c3;
        }
        __syncthreads();
#pragma unroll
        for (int ks = 0; ks < 2; ++ks) {
            bf16x8 a[4];
#pragma unroll
            for (int mi = 0; mi < 4; ++mi)
                a[mi] = *(const bf16x8*)(&sA[wm * 64 + mi * 16 + l16][ks * 32 + quad * 8]);
#pragma unroll
            for (int ni = 0; ni < 2; ++ni) {
                bf16x8 b1v = *(const bf16x8*)(&sB1[wn * 32 + ni * 16 + l16][ks * 32 + quad * 8]);
                bf16x8 b2v = *(const bf16x8*)(&sB2[wn * 32 + ni * 16 + l16][ks * 32 + quad * 8]);
#pragma unroll
                for (int mi = 0; mi < 4; ++mi) {
                    accg[mi][ni] = __builtin_amdgcn_mfma_f32_16x16x32_bf16(a[mi], b1v, accg[mi][ni], 0, 0, 0);
                    accu[mi][ni] = __builtin_amdgcn_mfma_f32_16x16x32_bf16(a[mi], b2v, accu[mi][ni], 0, 0, 0);
                }
            }
        }
        __syncthreads();
    }
    // epilogue: silu(g)*u -> bf16 act[p][i]
#pragma unroll
    for (int mi = 0; mi < 4; ++mi) {
#pragma unroll
        for (int r = 0; r < 4; ++r) {
            int row = wm * 64 + mi * 16 + quad * 4 + r;   // C/D: row = quad*4+reg
            int rr = row0 + row;
            if (rr < cnt) {
                size_t base = (size_t)(off + rr) * NI + i0 + wn * 32 + l16;   // col = lane&15
#pragma unroll
                for (int ni = 0; ni < 2; ++ni) {
                    float g = accg[mi][ni][r];
                    float u = accu[mi][ni][r];
                    float sv = g / (1.0f + __expf(-g)) * u;
                    act[base + ni * 16] = f2bf(sv);
                }
            }
        }
    }
}

// ---------------- pass 2: y[p] = act[p] @ w2[e]^T (per expert) ----------------
__global__ __launch_bounds__(256) void k_down(
    const unsigned short* __restrict__ act, const float* __restrict__ w2,
    const int* __restrict__ offs, const int* __restrict__ counts,
    unsigned short* __restrict__ ybuf) {
    const int e = blockIdx.z;
    const int cnt = counts[e];
    const int row0 = blockIdx.x * 128;
    if (row0 >= cnt) return;
    const int h0 = blockIdx.y * 64;
    const int off = offs[e];

    __shared__ unsigned short sA[128][72];
    __shared__ unsigned short sB[64][72];

    const int tid = threadIdx.x;
    const int lane = tid & 63, wid = tid >> 6;
    const int wm = wid & 1, wn = wid >> 1;
    const int quad = lane >> 4, l16 = lane & 15;

    const f32x4 zf = {0.f, 0.f, 0.f, 0.f};
    f32x4 acc[4][2];
#pragma unroll
    for (int mi = 0; mi < 4; ++mi)
#pragma unroll
        for (int ni = 0; ni < 2; ++ni) acc[mi][ni] = zf;

    const int ar = tid >> 3;
    const int ak = (tid & 7) * 8;
    const unsigned short* pa[4];
#pragma unroll
    for (int it = 0; it < 4; ++it) {
        int rr = row0 + ar + it * 32;
        int p = off + (rr < cnt ? rr : cnt - 1);
        pa[it] = act + (size_t)p * NI + ak;
    }
    const int br = tid >> 4;
    const int bk = (tid & 15) * 4;
    const float* pw2 = w2 + ((size_t)e * NH + h0 + br) * NI + bk;

    for (int k0 = 0; k0 < NI; k0 += 64) {
#pragma unroll
        for (int it = 0; it < 4; ++it) {
            const uint4 v = *(const uint4*)(pa[it] + k0);
            *(uint4*)(&sA[ar + it * 32][ak]) = v;
        }
#pragma unroll
        for (int it = 0; it < 4; ++it) {
            const float4 v2 = *(const float4*)(pw2 + (size_t)(it * 16) * NI + k0);
            ushort4 c2;
            c2.x = f2bf(v2.x); c2.y = f2bf(v2.y); c2.z = f2bf(v2.z); c2.w = f2bf(v2.w);
            *(ushort4*)(&sB[br + it * 16][bk]) = c2;
        }
        __syncthreads();
#pragma unroll
        for (int ks = 0; ks < 2; ++ks) {
            bf16x8 a[4];
#pragma unroll
            for (int mi = 0; mi < 4; ++mi)
                a[mi] = *(const bf16x8*)(&sA[wm * 64 + mi * 16 + l16][ks * 32 + quad * 8]);
#pragma unroll
            for (int ni = 0; ni < 2; ++ni) {
                bf16x8 bv = *(const bf16x8*)(&sB[wn * 32 + ni * 16 + l16][ks * 32 + quad * 8]);
#pragma unroll
                for (int mi = 0; mi < 4; ++mi)
                    acc[mi][ni] = __builtin_amdgcn_mfma_f32_16x16x32_bf16(a[mi], bv, acc[mi][ni], 0, 0, 0);
            }
        }
        __syncthreads();
    }
#pragma unroll
    for (int mi = 0; mi < 4; ++mi) {
#pragma unroll
        for (int r = 0; r < 4; ++r) {
            int row = wm * 64 + mi * 16 + quad * 4 + r;
            int rr = row0 + row;
            if (rr < cnt) {
                size_t base = (size_t)(off + rr) * NH + h0 + wn * 32 + l16;
#pragma unroll
                for (int ni = 0; ni < 2; ++ni)
                    ybuf[base + ni * 16] = f2bf(acc[mi][ni][r]);
            }
        }
    }
}

// ---------------- combine: out[t] = w0*y[p0] + w1*y[p1] ----------------
__global__ __launch_bounds__(256) void k_combine(const unsigned short* __restrict__ y,
                                                 const int* __restrict__ slot_pos,
                                                 const float* __restrict__ tw2,
                                                 float* __restrict__ out) {
    int g = blockIdx.x * 256 + threadIdx.x;   // one thread per 8 H-elements
    int t = g >> 8;                           // H/8 == 256
    int hc = (g & 255) * 8;
    int p0 = slot_pos[2 * t], p1 = slot_pos[2 * t + 1];
    float w0 = tw2[2 * t], w1v = tw2[2 * t + 1];
    ushort8v a = *(const ushort8v*)(y + (size_t)p0 * NH + hc);
    ushort8v b = *(const ushort8v*)(y + (size_t)p1 * NH + hc);
    float o[8];
#pragma unroll
    for (int j = 0; j < 8; ++j)
        o[j] = w0 * bf2f(a[j]) + w1v * bf2f(b[j]);
    float* po = out + (size_t)t * NH + hc;
    *(float4*)(po) = make_float4(o[0], o[1], o[2], o[3]);
    *(float4*)(po + 4) = make_float4(o[4], o[5], o[6], o[7]);
}

// ---------------- launch ----------------
extern "C" void kernel_launch(void* const* d_in, const int* in_sizes, int n_in,
                              void* d_out, int out_size, void* d_ws, size_t ws_size,
                              hipStream_t stream) {
    const float* x  = (const float*)d_in[0];
    const float* rl = (const float*)d_in[1];
    const float* w1 = (const float*)d_in[2];
    const float* w2 = (const float*)d_in[3];
    const float* w3 = (const float*)d_in[4];
    float* out = (float*)d_out;

    char* ws = (char*)d_ws;
    unsigned short* xbf = (unsigned short*)ws; ws += (size_t)T_TOK * NH * 2;
    unsigned short* act = (unsigned short*)ws; ws += (size_t)NS * NI * 2;
    unsigned short* ybuf = (unsigned short*)ws; ws += (size_t)NS * NH * 2;
    int*   tid2 = (int*)ws;       ws += (size_t)NS * 4;
    float* tw2  = (float*)ws;     ws += (size_t)NS * 4;
    int*   sorted_tok = (int*)ws; ws += (size_t)NS * 4;
    int*   slot_pos   = (int*)ws; ws += (size_t)NS * 4;
    int*   counts = (int*)ws;     ws += 256;
    int*   offs   = (int*)ws;     ws += 256;
    int*   pos    = (int*)ws;     ws += 256;

    k_prep<<<T_TOK * NH / 4 / 256, 256, 0, stream>>>(x, xbf, counts, pos);
    k_router<<<T_TOK / 256, 256, 0, stream>>>(rl, tid2, tw2, counts);
    k_scan<<<1, 64, 0, stream>>>(counts, offs);
    k_scatter<<<NS / 256, 256, 0, stream>>>(tid2, offs, pos, sorted_tok, slot_pos);
    dim3 g1(T_TOK / 128, NI / 64, NE);
    k_up<<<g1, 256, 0, stream>>>(xbf, w1, w3, sorted_tok, offs, counts, act);
    dim3 g2(T_TOK / 128, NH / 64, NE);
    k_down<<<g2, 256, 0, stream>>>(act, w2, offs, counts, ybuf);
    k_combine<<<T_TOK * NH / 8 / 256, 256, 0, stream>>>(ybuf, slot_pos, tw2, out);
}